// Round 4
// baseline (222.288 us; speedup 1.0000x reference)
//
#include <hip/hip_runtime.h>

#define D 64  // D_IN == D_OUT == 64

typedef unsigned short ushort_t;

__device__ __forceinline__ void fma4(float4& c, float a, const float4& b) {
  c.x = fmaf(a, b.x, c.x);
  c.y = fmaf(a, b.y, c.y);
  c.z = fmaf(a, b.z, c.z);
  c.w = fmaf(a, b.w, c.w);
}

__device__ __forceinline__ unsigned short f2bf(float f) {  // RNE pack
  unsigned u = __float_as_uint(f);
  return (unsigned short)((u + 0x7FFFu + ((u >> 16) & 1u)) >> 16);
}
__device__ __forceinline__ float bf2f(unsigned short h) {
  return __uint_as_float((unsigned)h << 16);
}

// ---------------- projection GEMM ----------------
// BF16OUT: store bf16 (proj buffer); else float (self-loop into out).
template <bool BF16OUT>
__device__ void proj_tile(const float* __restrict__ feat, const float* __restrict__ W,
                          void* __restrict__ outp, int N, int tileBase) {
  __shared__ float sW[64 * 64];
  __shared__ float sF[64 * 132];
  const int t = threadIdx.x;

  {
    const float4* Wv = (const float4*)W;
    float4* sWv = (float4*)sW;
    for (int k = t; k < 1024; k += 256) sWv[k] = Wv[k];
  }
  {
    const int row = t >> 1, half = t & 1;
    const int gr = tileBase + row;
    if (gr < N) {
      const float4* src = (const float4*)(feat + (size_t)gr * D + half * 32);
#pragma unroll
      for (int k = 0; k < 8; ++k) {
        float4 v = src[k];
        int i0 = half * 32 + k * 4;
        sF[(i0 + 0) * 132 + row] = v.x;
        sF[(i0 + 1) * 132 + row] = v.y;
        sF[(i0 + 2) * 132 + row] = v.z;
        sF[(i0 + 3) * 132 + row] = v.w;
      }
    } else {
#pragma unroll
      for (int k = 0; k < 8; ++k) {
        int i0 = half * 32 + k * 4;
        sF[(i0 + 0) * 132 + row] = 0.f;
        sF[(i0 + 1) * 132 + row] = 0.f;
        sF[(i0 + 2) * 132 + row] = 0.f;
        sF[(i0 + 3) * 132 + row] = 0.f;
      }
    }
  }
  __syncthreads();

  const int c0 = (t & 15) * 4;
  const int r0 = (t >> 4) * 8;
  float4 acc[8];
#pragma unroll
  for (int rr = 0; rr < 8; ++rr) acc[rr] = make_float4(0.f, 0.f, 0.f, 0.f);

#pragma unroll 8
  for (int i = 0; i < 64; ++i) {
    float4 w  = *(const float4*)&sW[i * 64 + c0];
    float4 a0 = *(const float4*)&sF[i * 132 + r0];
    float4 a1 = *(const float4*)&sF[i * 132 + r0 + 4];
    fma4(acc[0], a0.x, w); fma4(acc[1], a0.y, w);
    fma4(acc[2], a0.z, w); fma4(acc[3], a0.w, w);
    fma4(acc[4], a1.x, w); fma4(acc[5], a1.y, w);
    fma4(acc[6], a1.z, w); fma4(acc[7], a1.w, w);
  }

#pragma unroll
  for (int rr = 0; rr < 8; ++rr) {
    int gn = tileBase + r0 + rr;
    if (gn < N) {
      if (BF16OUT) {
        ushort4 h;
        h.x = f2bf(acc[rr].x); h.y = f2bf(acc[rr].y);
        h.z = f2bf(acc[rr].z); h.w = f2bf(acc[rr].w);
        *(ushort4*)((ushort_t*)outp + (size_t)gn * D + c0) = h;
      } else {
        *(float4*)((float*)outp + (size_t)gn * D + c0) = acc[rr];
      }
    }
  }
}

__global__ __launch_bounds__(256, 3) void proj_all(const float* __restrict__ feat,
                                                   const float* __restrict__ weight,
                                                   const float* __restrict__ loopw,
                                                   ushort_t* __restrict__ proj,
                                                   float* __restrict__ out, int N, int R) {
  const int m = blockIdx.y;
  if (m < R) {
    proj_tile<true>(feat, weight + (size_t)m * D * D, proj + (size_t)m * N * D, N,
                    blockIdx.x * 128);
  } else {
    proj_tile<false>(feat, loopw, out, N, blockIdx.x * 128);
  }
}

__global__ __launch_bounds__(256, 3) void proj_single(const float* __restrict__ feat,
                                                      const float* __restrict__ W,
                                                      float* __restrict__ o, int N) {
  proj_tile<false>(feat, W, o, N, blockIdx.x * 128);
}

// ---------------- CSR build ----------------
__global__ void zero_ints(int* __restrict__ p, int n) {
  int i = blockIdx.x * 256 + threadIdx.x;
  if (i < n) p[i] = 0;
}

__global__ void hist_dst2(const int* __restrict__ edst, int* __restrict__ deg, int E) {
  const int e = (blockIdx.x * 256 + threadIdx.x) * 2;
  if (e + 1 < E) {
    int2 d = *(const int2*)(edst + e);
    atomicAdd(&deg[d.x], 1);
    atomicAdd(&deg[d.y], 1);
  } else if (e < E) {
    atomicAdd(&deg[edst[e]], 1);
  }
}

// Two-level scan: (1) per-block sums of 1024 elements.
__global__ __launch_bounds__(256) void scan_partial(const int* __restrict__ deg,
                                                    int* __restrict__ bsum, int N) {
  const int t = threadIdx.x;
  const int base = blockIdx.x * 1024 + t * 4;
  int s = 0;
  if (base + 3 < N) {
    int4 v = *(const int4*)(deg + base);
    s = v.x + v.y + v.z + v.w;
  } else {
#pragma unroll
    for (int k = 0; k < 4; ++k) if (base + k < N) s += deg[base + k];
  }
  __shared__ int red[4];
#pragma unroll
  for (int m = 1; m < 64; m <<= 1) s += __shfl_xor(s, m);
  if ((t & 63) == 0) red[t >> 6] = s;
  __syncthreads();
  if (t == 0) bsum[blockIdx.x] = red[0] + red[1] + red[2] + red[3];
}

// (2) scan block sums, write total to off[N].  (boff may alias bsum.)
__global__ __launch_bounds__(256) void scan_bsum(const int* __restrict__ bsum,
                                                 int* __restrict__ boff,
                                                 int* __restrict__ off, int nb, int N) {
  __shared__ int s[256];
  __shared__ int carry_s;
  const int t = threadIdx.x;
  if (t == 0) carry_s = 0;
  __syncthreads();
  for (int base = 0; base < nb; base += 256) {
    int i = base + t;
    int v = (i < nb) ? bsum[i] : 0;
    s[t] = v;
    __syncthreads();
#pragma unroll
    for (int d = 1; d < 256; d <<= 1) {
      int u = (t >= d) ? s[t - d] : 0;
      __syncthreads();
      s[t] += u;
      __syncthreads();
    }
    int c = carry_s;
    if (i < nb) boff[i] = s[t] - v + c;
    __syncthreads();
    if (t == 0) carry_s = c + s[255];
    __syncthreads();
  }
  if (t == 0) off[N] = carry_s;
}

// (3) re-read degrees, in-block exclusive scan + block offset -> off, cursor.
__global__ __launch_bounds__(256) void scan_apply(const int* __restrict__ deg,
                                                  const int* __restrict__ boff,
                                                  int* __restrict__ off,
                                                  int* __restrict__ cursor, int N) {
  const int t = threadIdx.x;
  const int base = blockIdx.x * 1024 + t * 4;
  int v0 = 0, v1 = 0, v2 = 0, v3 = 0;
  if (base + 3 < N) {
    int4 v = *(const int4*)(deg + base);
    v0 = v.x; v1 = v.y; v2 = v.z; v3 = v.w;
  } else {
    if (base + 0 < N) v0 = deg[base + 0];
    if (base + 1 < N) v1 = deg[base + 1];
    if (base + 2 < N) v2 = deg[base + 2];
  }
  const int tsum = v0 + v1 + v2 + v3;
  __shared__ int s[256];
  s[t] = tsum;
  __syncthreads();
#pragma unroll
  for (int d = 1; d < 256; d <<= 1) {
    int u = (t >= d) ? s[t - d] : 0;
    __syncthreads();
    s[t] += u;
    __syncthreads();
  }
  int exc = s[t] - tsum + boff[blockIdx.x];
  const int o1 = exc + v0, o2 = o1 + v1, o3 = o2 + v2;
  if (base + 0 < N) { off[base + 0] = exc; cursor[base + 0] = exc; }
  if (base + 1 < N) { off[base + 1] = o1;  cursor[base + 1] = o1; }
  if (base + 2 < N) { off[base + 2] = o2;  cursor[base + 2] = o2; }
  if (base + 3 < N) { off[base + 3] = o3;  cursor[base + 3] = o3; }
}

// Scatter edge payloads (single 8B int2 per edge) into dst-sorted order.
__global__ void scatter_idx2(const int* __restrict__ esrc, const int* __restrict__ edst,
                             const int* __restrict__ etype, const float* __restrict__ att,
                             int* __restrict__ cursor, int2* __restrict__ payload, int E) {
  const int e = (blockIdx.x * 256 + threadIdx.x) * 2;
  if (e + 1 < E) {
    int2 s = *(const int2*)(esrc + e);
    int2 d = *(const int2*)(edst + e);
    int2 r = *(const int2*)(etype + e);
    float2 a = *(const float2*)(att + e);
    int p0 = atomicAdd(&cursor[d.x], 1);
    int p1 = atomicAdd(&cursor[d.y], 1);
    payload[p0] = make_int2(s.x | (r.x << 24), __float_as_int(a.x));
    payload[p1] = make_int2(s.y | (r.y << 24), __float_as_int(a.y));
  } else if (e < E) {
    int pos = atomicAdd(&cursor[edst[e]], 1);
    payload[pos] = make_int2(esrc[e] | (etype[e] << 24), __float_as_int(att[e]));
  }
}

// One node per 64-lane wave: 4 edge-subgroups x 16 lanes x (4 bf16 cols).
__global__ __launch_bounds__(256, 8) void node_gather(const int* __restrict__ off,
                                                      const int2* __restrict__ payload,
                                                      const ushort_t* __restrict__ proj,
                                                      const float* __restrict__ hbias,
                                                      float* __restrict__ out, int N) {
  const int n = (blockIdx.x * 256 + threadIdx.x) >> 6;
  if (n >= N) return;
  const int lane = threadIdx.x & 63;
  const int sub = lane >> 4;
  const int q = lane & 15;

  const int s0 = off[n], s1 = off[n + 1];
  float4 acc = make_float4(0.f, 0.f, 0.f, 0.f);
  float sa = 0.f;
  for (int e = s0 + sub; e < s1; e += 4) {
    const int2 pe = payload[e];
    const float a = __int_as_float(pe.y);
    const int src = pe.x & 0x00FFFFFF;
    const int r = ((unsigned)pe.x) >> 24;
    const ushort4 p = *(const ushort4*)(proj + ((size_t)r * N + src) * D + q * 4);
    acc.x = fmaf(a, bf2f(p.x), acc.x);
    acc.y = fmaf(a, bf2f(p.y), acc.y);
    acc.z = fmaf(a, bf2f(p.z), acc.z);
    acc.w = fmaf(a, bf2f(p.w), acc.w);
    sa += a;
  }
#pragma unroll
  for (int m = 16; m < 64; m <<= 1) {
    acc.x += __shfl_xor(acc.x, m);
    acc.y += __shfl_xor(acc.y, m);
    acc.z += __shfl_xor(acc.z, m);
    acc.w += __shfl_xor(acc.w, m);
    sa += __shfl_xor(sa, m);
  }
  if (sub == 0) {
    const float4 hb = ((const float4*)hbias)[q];
    float* op = out + (size_t)n * D + q * 4;
    float4 cur = *(float4*)op;      // self-loop already there
    cur.x += acc.x + sa * hb.x;
    cur.y += acc.y + sa * hb.y;
    cur.z += acc.z + sa * hb.z;
    cur.w += acc.w + sa * hb.w;
    *(float4*)op = cur;
  }
}

// ---------------- fallback: atomic scatter (float proj) ----------------
__global__ __launch_bounds__(256, 8) void edge_scatter(const int* __restrict__ esrc,
                                                       const int* __restrict__ edst,
                                                       const int* __restrict__ etype,
                                                       const float* __restrict__ att,
                                                       const float* __restrict__ proj,
                                                       const float* __restrict__ hbias,
                                                       float* __restrict__ out,
                                                       int E, int N, int relFilter) {
  const int t = blockIdx.x * 256 + threadIdx.x;
  const int wave = t >> 6;
  const int lane = threadIdx.x & 63;
  const int sub = lane >> 4;
  const int q = lane & 15;
  const long e = (long)wave * 4 + sub;
  if (e >= E) return;
  const int r = etype[e];
  if (relFilter >= 0 && r != relFilter) return;
  const int s = esrc[e];
  const int dn = edst[e];
  const float a = att[e];
  const size_t base = (relFilter >= 0) ? (size_t)s * D : ((size_t)r * N + s) * D;
  const float4 hb = ((const float4*)hbias)[q];
  const float4 p = *(const float4*)(proj + base + q * 4);
  float* op = out + (size_t)dn * D + q * 4;
  unsafeAtomicAdd(op + 0, (p.x + hb.x) * a);
  unsafeAtomicAdd(op + 1, (p.y + hb.y) * a);
  unsafeAtomicAdd(op + 2, (p.z + hb.z) * a);
  unsafeAtomicAdd(op + 3, (p.w + hb.w) * a);
}

extern "C" void kernel_launch(void* const* d_in, const int* in_sizes, int n_in,
                              void* d_out, int out_size, void* d_ws, size_t ws_size,
                              hipStream_t stream) {
  const float* feat   = (const float*)d_in[0];
  const int* esrc     = (const int*)d_in[1];
  const int* edst     = (const int*)d_in[2];
  const int* etype    = (const int*)d_in[3];
  const float* att    = (const float*)d_in[4];
  const float* weight = (const float*)d_in[5];
  const float* hbias  = (const float*)d_in[6];
  const float* loopw  = (const float*)d_in[7];
  float* out = (float*)d_out;

  const int N = in_sizes[0] / D;          // 50000
  const int E = in_sizes[1];              // 800000
  const int R = in_sizes[5] / (D * D);    // 8

  const int Npad = (N + 3) & ~3;
  const int nb = (N + 1023) / 1024;

  // Sorted-CSR fast path layout (bf16 proj):
  const size_t projBytes = (size_t)R * N * D * 2;              // 16B-aligned count
  const size_t intCount  = (size_t)Npad + (size_t)(N + 1) + (size_t)N + (size_t)nb;
  const size_t payOff    = (projBytes + intCount * 4 + 7) & ~(size_t)7;
  const size_t needSorted = payOff + (size_t)E * 8;
  const size_t needAtomic = (size_t)R * N * D * 4;             // float proj fallback

  const int tilesN = (N + 127) / 128;
  const int epairBlocks = ((E + 1) / 2 + 255) / 256;

  if (ws_size >= needSorted) {
    ushort_t* proj = (ushort_t*)d_ws;
    int* deg    = (int*)((char*)d_ws + projBytes);  // Npad ints, 16B-aligned
    int* off    = deg + Npad;                       // N+1
    int* cursor = off + (N + 1);                    // N
    int* bsum   = cursor + N;                       // nb (doubles as boff)
    int2* payload = (int2*)((char*)d_ws + payOff);  // E

    proj_all<<<dim3(tilesN, R + 1), 256, 0, stream>>>(feat, weight, loopw, proj, out, N, R);
    zero_ints<<<(N + 255) / 256, 256, 0, stream>>>(deg, N);
    hist_dst2<<<epairBlocks, 256, 0, stream>>>(edst, deg, E);
    scan_partial<<<nb, 256, 0, stream>>>(deg, bsum, N);
    scan_bsum<<<1, 256, 0, stream>>>(bsum, bsum, off, nb, N);
    scan_apply<<<nb, 256, 0, stream>>>(deg, bsum, off, cursor, N);
    scatter_idx2<<<epairBlocks, 256, 0, stream>>>(esrc, edst, etype, att, cursor, payload, E);
    node_gather<<<(N + 3) / 4, 256, 0, stream>>>(off, payload, proj, hbias, out, N);
  } else if (ws_size >= needAtomic) {
    float* proj = (float*)d_ws;
    const int eblocks16 = (E + 15) / 16;
    proj_single<<<tilesN, 256, 0, stream>>>(feat, loopw, out, N);
    for (int r = 0; r < R; ++r) {
      proj_single<<<tilesN, 256, 0, stream>>>(feat, weight + (size_t)r * D * D,
                                              (float*)d_ws, N);
      edge_scatter<<<eblocks16, 256, 0, stream>>>(esrc, edst, etype, att, (float*)d_ws,
                                                  hbias, out, E, N, r);
    }
    (void)proj;
  } else {
    // Minimal-scratch fallback: needs N*D floats.
    const int eblocks16 = (E + 15) / 16;
    proj_single<<<tilesN, 256, 0, stream>>>(feat, loopw, out, N);
    for (int r = 0; r < R; ++r) {
      proj_single<<<tilesN, 256, 0, stream>>>(feat, weight + (size_t)r * D * D,
                                              (float*)d_ws, N);
      edge_scatter<<<eblocks16, 256, 0, stream>>>(esrc, edst, etype, att, (float*)d_ws,
                                                  hbias, out, E, N, r);
    }
  }
}

// Round 5
// 198.802 us; speedup vs baseline: 1.1181x; 1.1181x over previous
//
#include <hip/hip_runtime.h>

#define D 64  // D_IN == D_OUT == 64

typedef unsigned short ushort_t;

__device__ __forceinline__ void fma4(float4& c, float a, const float4& b) {
  c.x = fmaf(a, b.x, c.x);
  c.y = fmaf(a, b.y, c.y);
  c.z = fmaf(a, b.z, c.z);
  c.w = fmaf(a, b.w, c.w);
}

__device__ __forceinline__ unsigned short f2bf(float f) {  // RNE pack
  unsigned u = __float_as_uint(f);
  return (unsigned short)((u + 0x7FFFu + ((u >> 16) & 1u)) >> 16);
}
__device__ __forceinline__ float bf2f(unsigned short h) {
  return __uint_as_float((unsigned)h << 16);
}

// ---------------- fused projection GEMM ----------------
// One block = 128 nodes. Stage feat tile ONCE, loop over R rel-weights (bf16 out)
// + self-loop weight (fp32 into out). LDS declared once: 50176 B -> 3 blocks/CU.
__global__ __launch_bounds__(256, 3) void proj_fused(const float* __restrict__ feat,
                                                     const float* __restrict__ weight,
                                                     const float* __restrict__ loopw,
                                                     ushort_t* __restrict__ proj,
                                                     float* __restrict__ out, int N, int R) {
  __shared__ float sW[64 * 64];
  __shared__ float sF[64 * 132];
  const int t = threadIdx.x;
  const int tileBase = blockIdx.x * 128;

  // Stage feat tile transposed: sF[i][node_local], 2 threads per row.
  {
    const int row = t >> 1, half = t & 1;
    const int gr = tileBase + row;
    if (gr < N) {
      const float4* src = (const float4*)(feat + (size_t)gr * D + half * 32);
#pragma unroll
      for (int k = 0; k < 8; ++k) {
        float4 v = src[k];
        int i0 = half * 32 + k * 4;
        sF[(i0 + 0) * 132 + row] = v.x;
        sF[(i0 + 1) * 132 + row] = v.y;
        sF[(i0 + 2) * 132 + row] = v.z;
        sF[(i0 + 3) * 132 + row] = v.w;
      }
    } else {
#pragma unroll
      for (int k = 0; k < 8; ++k) {
        int i0 = half * 32 + k * 4;
        sF[(i0 + 0) * 132 + row] = 0.f;
        sF[(i0 + 1) * 132 + row] = 0.f;
        sF[(i0 + 2) * 132 + row] = 0.f;
        sF[(i0 + 3) * 132 + row] = 0.f;
      }
    }
  }

  const int c0 = (t & 15) * 4;
  const int r0 = (t >> 4) * 8;

  for (int m = 0; m <= R; ++m) {
    const float* W = (m < R) ? weight + (size_t)m * D * D : loopw;
    __syncthreads();   // previous iteration done reading sW (and sF staging on m=0)
    {
      const float4* Wv = (const float4*)W;
      float4* sWv = (float4*)sW;
      for (int k = t; k < 1024; k += 256) sWv[k] = Wv[k];
    }
    __syncthreads();

    float4 acc[8];
#pragma unroll
    for (int rr = 0; rr < 8; ++rr) acc[rr] = make_float4(0.f, 0.f, 0.f, 0.f);

#pragma unroll 8
    for (int i = 0; i < 64; ++i) {
      float4 w  = *(const float4*)&sW[i * 64 + c0];
      float4 a0 = *(const float4*)&sF[i * 132 + r0];
      float4 a1 = *(const float4*)&sF[i * 132 + r0 + 4];
      fma4(acc[0], a0.x, w); fma4(acc[1], a0.y, w);
      fma4(acc[2], a0.z, w); fma4(acc[3], a0.w, w);
      fma4(acc[4], a1.x, w); fma4(acc[5], a1.y, w);
      fma4(acc[6], a1.z, w); fma4(acc[7], a1.w, w);
    }

    if (m < R) {
      ushort_t* op = proj + (size_t)m * N * D;
#pragma unroll
      for (int rr = 0; rr < 8; ++rr) {
        int gn = tileBase + r0 + rr;
        if (gn < N) {
          ushort4 h;
          h.x = f2bf(acc[rr].x); h.y = f2bf(acc[rr].y);
          h.z = f2bf(acc[rr].z); h.w = f2bf(acc[rr].w);
          *(ushort4*)(op + (size_t)gn * D + c0) = h;
        }
      }
    } else {
#pragma unroll
      for (int rr = 0; rr < 8; ++rr) {
        int gn = tileBase + r0 + rr;
        if (gn < N) *(float4*)(out + (size_t)gn * D + c0) = acc[rr];
      }
    }
  }
}

// ---------------- float-only tile (fallback paths) ----------------
__global__ __launch_bounds__(256, 3) void proj_single(const float* __restrict__ feat,
                                                      const float* __restrict__ W,
                                                      float* __restrict__ outp, int N) {
  __shared__ float sW[64 * 64];
  __shared__ float sF[64 * 132];
  const int t = threadIdx.x;
  const int tileBase = blockIdx.x * 128;

  {
    const float4* Wv = (const float4*)W;
    float4* sWv = (float4*)sW;
    for (int k = t; k < 1024; k += 256) sWv[k] = Wv[k];
  }
  {
    const int row = t >> 1, half = t & 1;
    const int gr = tileBase + row;
    if (gr < N) {
      const float4* src = (const float4*)(feat + (size_t)gr * D + half * 32);
#pragma unroll
      for (int k = 0; k < 8; ++k) {
        float4 v = src[k];
        int i0 = half * 32 + k * 4;
        sF[(i0 + 0) * 132 + row] = v.x;
        sF[(i0 + 1) * 132 + row] = v.y;
        sF[(i0 + 2) * 132 + row] = v.z;
        sF[(i0 + 3) * 132 + row] = v.w;
      }
    } else {
#pragma unroll
      for (int k = 0; k < 8; ++k) {
        int i0 = half * 32 + k * 4;
        sF[(i0 + 0) * 132 + row] = 0.f;
        sF[(i0 + 1) * 132 + row] = 0.f;
        sF[(i0 + 2) * 132 + row] = 0.f;
        sF[(i0 + 3) * 132 + row] = 0.f;
      }
    }
  }
  __syncthreads();

  const int c0 = (t & 15) * 4;
  const int r0 = (t >> 4) * 8;
  float4 acc[8];
#pragma unroll
  for (int rr = 0; rr < 8; ++rr) acc[rr] = make_float4(0.f, 0.f, 0.f, 0.f);

#pragma unroll 8
  for (int i = 0; i < 64; ++i) {
    float4 w  = *(const float4*)&sW[i * 64 + c0];
    float4 a0 = *(const float4*)&sF[i * 132 + r0];
    float4 a1 = *(const float4*)&sF[i * 132 + r0 + 4];
    fma4(acc[0], a0.x, w); fma4(acc[1], a0.y, w);
    fma4(acc[2], a0.z, w); fma4(acc[3], a0.w, w);
    fma4(acc[4], a1.x, w); fma4(acc[5], a1.y, w);
    fma4(acc[6], a1.z, w); fma4(acc[7], a1.w, w);
  }

#pragma unroll
  for (int rr = 0; rr < 8; ++rr) {
    int gn = tileBase + r0 + rr;
    if (gn < N) *(float4*)(outp + (size_t)gn * D + c0) = acc[rr];
  }
}

// ---------------- CSR build ----------------
__global__ void zero_ints(int* __restrict__ p, int n) {
  int i = blockIdx.x * 256 + threadIdx.x;
  if (i < n) p[i] = 0;
}

__global__ void hist_dst2(const int* __restrict__ edst, int* __restrict__ deg, int E) {
  const int e = (blockIdx.x * 256 + threadIdx.x) * 2;
  if (e + 1 < E) {
    int2 d = *(const int2*)(edst + e);
    atomicAdd(&deg[d.x], 1);
    atomicAdd(&deg[d.y], 1);
  } else if (e < E) {
    atomicAdd(&deg[edst[e]], 1);
  }
}

__global__ __launch_bounds__(256) void scan_partial(const int* __restrict__ deg,
                                                    int* __restrict__ bsum, int N) {
  const int t = threadIdx.x;
  const int base = blockIdx.x * 1024 + t * 4;
  int s = 0;
  if (base + 3 < N) {
    int4 v = *(const int4*)(deg + base);
    s = v.x + v.y + v.z + v.w;
  } else {
#pragma unroll
    for (int k = 0; k < 4; ++k) if (base + k < N) s += deg[base + k];
  }
  __shared__ int red[4];
#pragma unroll
  for (int m = 1; m < 64; m <<= 1) s += __shfl_xor(s, m);
  if ((t & 63) == 0) red[t >> 6] = s;
  __syncthreads();
  if (t == 0) bsum[blockIdx.x] = red[0] + red[1] + red[2] + red[3];
}

__global__ __launch_bounds__(256) void scan_bsum(const int* __restrict__ bsum,
                                                 int* __restrict__ boff,
                                                 int* __restrict__ off, int nb, int N) {
  __shared__ int s[256];
  __shared__ int carry_s;
  const int t = threadIdx.x;
  if (t == 0) carry_s = 0;
  __syncthreads();
  for (int base = 0; base < nb; base += 256) {
    int i = base + t;
    int v = (i < nb) ? bsum[i] : 0;
    s[t] = v;
    __syncthreads();
#pragma unroll
    for (int d = 1; d < 256; d <<= 1) {
      int u = (t >= d) ? s[t - d] : 0;
      __syncthreads();
      s[t] += u;
      __syncthreads();
    }
    int c = carry_s;
    if (i < nb) boff[i] = s[t] - v + c;
    __syncthreads();
    if (t == 0) carry_s = c + s[255];
    __syncthreads();
  }
  if (t == 0) off[N] = carry_s;
}

__global__ __launch_bounds__(256) void scan_apply(const int* __restrict__ deg,
                                                  const int* __restrict__ boff,
                                                  int* __restrict__ off,
                                                  int* __restrict__ cursor, int N) {
  const int t = threadIdx.x;
  const int base = blockIdx.x * 1024 + t * 4;
  int v0 = 0, v1 = 0, v2 = 0, v3 = 0;
  if (base + 3 < N) {
    int4 v = *(const int4*)(deg + base);
    v0 = v.x; v1 = v.y; v2 = v.z; v3 = v.w;
  } else {
    if (base + 0 < N) v0 = deg[base + 0];
    if (base + 1 < N) v1 = deg[base + 1];
    if (base + 2 < N) v2 = deg[base + 2];
  }
  const int tsum = v0 + v1 + v2 + v3;
  __shared__ int s[256];
  s[t] = tsum;
  __syncthreads();
#pragma unroll
  for (int d = 1; d < 256; d <<= 1) {
    int u = (t >= d) ? s[t - d] : 0;
    __syncthreads();
    s[t] += u;
    __syncthreads();
  }
  int exc = s[t] - tsum + boff[blockIdx.x];
  const int o1 = exc + v0, o2 = o1 + v1, o3 = o2 + v2;
  if (base + 0 < N) { off[base + 0] = exc; cursor[base + 0] = exc; }
  if (base + 1 < N) { off[base + 1] = o1;  cursor[base + 1] = o1; }
  if (base + 2 < N) { off[base + 2] = o2;  cursor[base + 2] = o2; }
  if (base + 3 < N) { off[base + 3] = o3;  cursor[base + 3] = o3; }
}

// Scatter edge payloads (single 8B int2 per edge) into dst-sorted order.
__global__ void scatter_idx2(const int* __restrict__ esrc, const int* __restrict__ edst,
                             const int* __restrict__ etype, const float* __restrict__ att,
                             int* __restrict__ cursor, int2* __restrict__ payload, int E) {
  const int e = (blockIdx.x * 256 + threadIdx.x) * 2;
  if (e + 1 < E) {
    int2 s = *(const int2*)(esrc + e);
    int2 d = *(const int2*)(edst + e);
    int2 r = *(const int2*)(etype + e);
    float2 a = *(const float2*)(att + e);
    int p0 = atomicAdd(&cursor[d.x], 1);
    int p1 = atomicAdd(&cursor[d.y], 1);
    payload[p0] = make_int2(s.x | (r.x << 24), __float_as_int(a.x));
    payload[p1] = make_int2(s.y | (r.y << 24), __float_as_int(a.y));
  } else if (e < E) {
    int pos = atomicAdd(&cursor[edst[e]], 1);
    payload[pos] = make_int2(esrc[e] | (etype[e] << 24), __float_as_int(att[e]));
  }
}

// One node per 64-lane wave: 4 edge-subgroups x 16 lanes x (4 bf16 cols).
__global__ __launch_bounds__(256, 8) void node_gather(const int* __restrict__ off,
                                                      const int2* __restrict__ payload,
                                                      const ushort_t* __restrict__ proj,
                                                      const float* __restrict__ hbias,
                                                      float* __restrict__ out, int N) {
  const int n = (blockIdx.x * 256 + threadIdx.x) >> 6;
  if (n >= N) return;
  const int lane = threadIdx.x & 63;
  const int sub = lane >> 4;
  const int q = lane & 15;

  const int s0 = off[n], s1 = off[n + 1];
  float4 acc = make_float4(0.f, 0.f, 0.f, 0.f);
  float sa = 0.f;
  for (int e = s0 + sub; e < s1; e += 4) {
    const int2 pe = payload[e];
    const float a = __int_as_float(pe.y);
    const int src = pe.x & 0x00FFFFFF;
    const int r = ((unsigned)pe.x) >> 24;
    const ushort4 p = *(const ushort4*)(proj + ((size_t)r * N + src) * D + q * 4);
    acc.x = fmaf(a, bf2f(p.x), acc.x);
    acc.y = fmaf(a, bf2f(p.y), acc.y);
    acc.z = fmaf(a, bf2f(p.z), acc.z);
    acc.w = fmaf(a, bf2f(p.w), acc.w);
    sa += a;
  }
#pragma unroll
  for (int m = 16; m < 64; m <<= 1) {
    acc.x += __shfl_xor(acc.x, m);
    acc.y += __shfl_xor(acc.y, m);
    acc.z += __shfl_xor(acc.z, m);
    acc.w += __shfl_xor(acc.w, m);
    sa += __shfl_xor(sa, m);
  }
  if (sub == 0) {
    const float4 hb = ((const float4*)hbias)[q];
    float* op = out + (size_t)n * D + q * 4;
    float4 cur = *(float4*)op;      // self-loop already there
    cur.x += acc.x + sa * hb.x;
    cur.y += acc.y + sa * hb.y;
    cur.z += acc.z + sa * hb.z;
    cur.w += acc.w + sa * hb.w;
    *(float4*)op = cur;
  }
}

// ---------------- fallback: atomic scatter (float proj) ----------------
__global__ __launch_bounds__(256, 8) void edge_scatter(const int* __restrict__ esrc,
                                                       const int* __restrict__ edst,
                                                       const int* __restrict__ etype,
                                                       const float* __restrict__ att,
                                                       const float* __restrict__ proj,
                                                       const float* __restrict__ hbias,
                                                       float* __restrict__ out,
                                                       int E, int N, int relFilter) {
  const int t = blockIdx.x * 256 + threadIdx.x;
  const int wave = t >> 6;
  const int lane = threadIdx.x & 63;
  const int sub = lane >> 4;
  const int q = lane & 15;
  const long e = (long)wave * 4 + sub;
  if (e >= E) return;
  const int r = etype[e];
  if (relFilter >= 0 && r != relFilter) return;
  const int s = esrc[e];
  const int dn = edst[e];
  const float a = att[e];
  const size_t base = (relFilter >= 0) ? (size_t)s * D : ((size_t)r * N + s) * D;
  const float4 hb = ((const float4*)hbias)[q];
  const float4 p = *(const float4*)(proj + base + q * 4);
  float* op = out + (size_t)dn * D + q * 4;
  unsafeAtomicAdd(op + 0, (p.x + hb.x) * a);
  unsafeAtomicAdd(op + 1, (p.y + hb.y) * a);
  unsafeAtomicAdd(op + 2, (p.z + hb.z) * a);
  unsafeAtomicAdd(op + 3, (p.w + hb.w) * a);
}

extern "C" void kernel_launch(void* const* d_in, const int* in_sizes, int n_in,
                              void* d_out, int out_size, void* d_ws, size_t ws_size,
                              hipStream_t stream) {
  const float* feat   = (const float*)d_in[0];
  const int* esrc     = (const int*)d_in[1];
  const int* edst     = (const int*)d_in[2];
  const int* etype    = (const int*)d_in[3];
  const float* att    = (const float*)d_in[4];
  const float* weight = (const float*)d_in[5];
  const float* hbias  = (const float*)d_in[6];
  const float* loopw  = (const float*)d_in[7];
  float* out = (float*)d_out;

  const int N = in_sizes[0] / D;          // 50000
  const int E = in_sizes[1];              // 800000
  const int R = in_sizes[5] / (D * D);    // 8

  const int Npad = (N + 3) & ~3;
  const int nb = (N + 1023) / 1024;

  // Sorted-CSR fast path layout (bf16 proj):
  const size_t projBytes = (size_t)R * N * D * 2;
  const size_t intCount  = (size_t)Npad + (size_t)(N + 1) + (size_t)N + (size_t)nb;
  const size_t payOff    = (projBytes + intCount * 4 + 7) & ~(size_t)7;
  const size_t needSorted = payOff + (size_t)E * 8;
  const size_t needAtomic = (size_t)N * D * 4;

  const int tilesN = (N + 127) / 128;
  const int epairBlocks = ((E + 1) / 2 + 255) / 256;

  if (ws_size >= needSorted) {
    ushort_t* proj = (ushort_t*)d_ws;
    int* deg    = (int*)((char*)d_ws + projBytes);  // Npad ints, 16B-aligned
    int* off    = deg + Npad;                       // N+1
    int* cursor = off + (N + 1);                    // N
    int* bsum   = cursor + N;                       // nb (doubles as boff)
    int2* payload = (int2*)((char*)d_ws + payOff);  // E

    proj_fused<<<tilesN, 256, 0, stream>>>(feat, weight, loopw, proj, out, N, R);
    zero_ints<<<(N + 255) / 256, 256, 0, stream>>>(deg, N);
    hist_dst2<<<epairBlocks, 256, 0, stream>>>(edst, deg, E);
    scan_partial<<<nb, 256, 0, stream>>>(deg, bsum, N);
    scan_bsum<<<1, 256, 0, stream>>>(bsum, bsum, off, nb, N);
    scan_apply<<<nb, 256, 0, stream>>>(deg, bsum, off, cursor, N);
    scatter_idx2<<<epairBlocks, 256, 0, stream>>>(esrc, edst, etype, att, cursor, payload, E);
    node_gather<<<(N + 3) / 4, 256, 0, stream>>>(off, payload, proj, hbias, out, N);
  } else {
    // Minimal-scratch fallback: needs N*D floats.
    const int eblocks16 = (E + 15) / 16;
    proj_single<<<tilesN, 256, 0, stream>>>(feat, loopw, out, N);
    for (int r = 0; r < R; ++r) {
      proj_single<<<tilesN, 256, 0, stream>>>(feat, weight + (size_t)r * D * D,
                                              (float*)d_ws, N);
      edge_scatter<<<eblocks16, 256, 0, stream>>>(esrc, edst, etype, att, (float*)d_ws,
                                                  hbias, out, E, N, r);
    }
    (void)needAtomic;
  }
}

// Round 6
// 191.216 us; speedup vs baseline: 1.1625x; 1.0397x over previous
//
#include <hip/hip_runtime.h>

#define D 64  // D_IN == D_OUT == 64

typedef unsigned short ushort_t;

__device__ __forceinline__ void fma4(float4& c, float a, const float4& b) {
  c.x = fmaf(a, b.x, c.x);
  c.y = fmaf(a, b.y, c.y);
  c.z = fmaf(a, b.z, c.z);
  c.w = fmaf(a, b.w, c.w);
}

__device__ __forceinline__ unsigned short f2bf(float f) {  // RNE pack
  unsigned u = __float_as_uint(f);
  return (unsigned short)((u + 0x7FFFu + ((u >> 16) & 1u)) >> 16);
}
__device__ __forceinline__ float bf2f(unsigned short h) {
  return __uint_as_float((unsigned)h << 16);
}

// ---------------- fused projection GEMM ----------------
// One block = 128 nodes x 3 weight matrices (blockIdx.y picks the group).
// Matrices 0..R-1 -> bf16 proj; matrix R -> self-loop fp32 into out.
// Grid = tilesN x ceil((R+1)/3) -> ~3 blocks/CU (LDS-limited), waves hide latency.
__global__ __launch_bounds__(256, 3) void proj_fused(const float* __restrict__ feat,
                                                     const float* __restrict__ weight,
                                                     const float* __restrict__ loopw,
                                                     ushort_t* __restrict__ proj,
                                                     float* __restrict__ out, int N, int R) {
  __shared__ float sW[64 * 64];
  __shared__ float sF[64 * 132];
  const int t = threadIdx.x;
  const int tileBase = blockIdx.x * 128;
  const int m0 = blockIdx.y * 3;

  // Stage feat tile transposed: sF[i][node_local], 2 threads per row.
  {
    const int row = t >> 1, half = t & 1;
    const int gr = tileBase + row;
    if (gr < N) {
      const float4* src = (const float4*)(feat + (size_t)gr * D + half * 32);
#pragma unroll
      for (int k = 0; k < 8; ++k) {
        float4 v = src[k];
        int i0 = half * 32 + k * 4;
        sF[(i0 + 0) * 132 + row] = v.x;
        sF[(i0 + 1) * 132 + row] = v.y;
        sF[(i0 + 2) * 132 + row] = v.z;
        sF[(i0 + 3) * 132 + row] = v.w;
      }
    } else {
#pragma unroll
      for (int k = 0; k < 8; ++k) {
        int i0 = half * 32 + k * 4;
        sF[(i0 + 0) * 132 + row] = 0.f;
        sF[(i0 + 1) * 132 + row] = 0.f;
        sF[(i0 + 2) * 132 + row] = 0.f;
        sF[(i0 + 3) * 132 + row] = 0.f;
      }
    }
  }

  const int c0 = (t & 15) * 4;
  const int r0 = (t >> 4) * 8;

  for (int j = 0; j < 3; ++j) {
    const int m = m0 + j;
    if (m > R) break;
    const float* W = (m < R) ? weight + (size_t)m * D * D : loopw;
    __syncthreads();   // prev iter done reading sW (and sF staging on j=0)
    {
      const float4* Wv = (const float4*)W;
      float4* sWv = (float4*)sW;
      for (int k = t; k < 1024; k += 256) sWv[k] = Wv[k];
    }
    __syncthreads();

    float4 acc[8];
#pragma unroll
    for (int rr = 0; rr < 8; ++rr) acc[rr] = make_float4(0.f, 0.f, 0.f, 0.f);

#pragma unroll 8
    for (int i = 0; i < 64; ++i) {
      float4 w  = *(const float4*)&sW[i * 64 + c0];
      float4 a0 = *(const float4*)&sF[i * 132 + r0];
      float4 a1 = *(const float4*)&sF[i * 132 + r0 + 4];
      fma4(acc[0], a0.x, w); fma4(acc[1], a0.y, w);
      fma4(acc[2], a0.z, w); fma4(acc[3], a0.w, w);
      fma4(acc[4], a1.x, w); fma4(acc[5], a1.y, w);
      fma4(acc[6], a1.z, w); fma4(acc[7], a1.w, w);
    }

    if (m < R) {
      ushort_t* op = proj + (size_t)m * N * D;
#pragma unroll
      for (int rr = 0; rr < 8; ++rr) {
        int gn = tileBase + r0 + rr;
        if (gn < N) {
          ushort4 h;
          h.x = f2bf(acc[rr].x); h.y = f2bf(acc[rr].y);
          h.z = f2bf(acc[rr].z); h.w = f2bf(acc[rr].w);
          *(ushort4*)(op + (size_t)gn * D + c0) = h;
        }
      }
    } else {
#pragma unroll
      for (int rr = 0; rr < 8; ++rr) {
        int gn = tileBase + r0 + rr;
        if (gn < N) *(float4*)(out + (size_t)gn * D + c0) = acc[rr];
      }
    }
  }
}

// ---------------- float-only tile (fallback paths) ----------------
__global__ __launch_bounds__(256, 3) void proj_single(const float* __restrict__ feat,
                                                      const float* __restrict__ W,
                                                      float* __restrict__ outp, int N) {
  __shared__ float sW[64 * 64];
  __shared__ float sF[64 * 132];
  const int t = threadIdx.x;
  const int tileBase = blockIdx.x * 128;

  {
    const float4* Wv = (const float4*)W;
    float4* sWv = (float4*)sW;
    for (int k = t; k < 1024; k += 256) sWv[k] = Wv[k];
  }
  {
    const int row = t >> 1, half = t & 1;
    const int gr = tileBase + row;
    if (gr < N) {
      const float4* src = (const float4*)(feat + (size_t)gr * D + half * 32);
#pragma unroll
      for (int k = 0; k < 8; ++k) {
        float4 v = src[k];
        int i0 = half * 32 + k * 4;
        sF[(i0 + 0) * 132 + row] = v.x;
        sF[(i0 + 1) * 132 + row] = v.y;
        sF[(i0 + 2) * 132 + row] = v.z;
        sF[(i0 + 3) * 132 + row] = v.w;
      }
    } else {
#pragma unroll
      for (int k = 0; k < 8; ++k) {
        int i0 = half * 32 + k * 4;
        sF[(i0 + 0) * 132 + row] = 0.f;
        sF[(i0 + 1) * 132 + row] = 0.f;
        sF[(i0 + 2) * 132 + row] = 0.f;
        sF[(i0 + 3) * 132 + row] = 0.f;
      }
    }
  }
  __syncthreads();

  const int c0 = (t & 15) * 4;
  const int r0 = (t >> 4) * 8;
  float4 acc[8];
#pragma unroll
  for (int rr = 0; rr < 8; ++rr) acc[rr] = make_float4(0.f, 0.f, 0.f, 0.f);

#pragma unroll 8
  for (int i = 0; i < 64; ++i) {
    float4 w  = *(const float4*)&sW[i * 64 + c0];
    float4 a0 = *(const float4*)&sF[i * 132 + r0];
    float4 a1 = *(const float4*)&sF[i * 132 + r0 + 4];
    fma4(acc[0], a0.x, w); fma4(acc[1], a0.y, w);
    fma4(acc[2], a0.z, w); fma4(acc[3], a0.w, w);
    fma4(acc[4], a1.x, w); fma4(acc[5], a1.y, w);
    fma4(acc[6], a1.z, w); fma4(acc[7], a1.w, w);
  }

#pragma unroll
  for (int rr = 0; rr < 8; ++rr) {
    int gn = tileBase + r0 + rr;
    if (gn < N) *(float4*)(outp + (size_t)gn * D + c0) = acc[rr];
  }
}

// ---------------- CSR build ----------------
__global__ void zero_ints(int* __restrict__ p, int n) {
  int i = blockIdx.x * 256 + threadIdx.x;
  if (i < n) p[i] = 0;
}

__global__ void hist_dst2(const int* __restrict__ edst, int* __restrict__ deg, int E) {
  const int e = (blockIdx.x * 256 + threadIdx.x) * 2;
  if (e + 1 < E) {
    int2 d = *(const int2*)(edst + e);
    atomicAdd(&deg[d.x], 1);
    atomicAdd(&deg[d.y], 1);
  } else if (e < E) {
    atomicAdd(&deg[edst[e]], 1);
  }
}

__global__ __launch_bounds__(256) void scan_partial(const int* __restrict__ deg,
                                                    int* __restrict__ bsum, int N) {
  const int t = threadIdx.x;
  const int base = blockIdx.x * 1024 + t * 4;
  int s = 0;
  if (base + 3 < N) {
    int4 v = *(const int4*)(deg + base);
    s = v.x + v.y + v.z + v.w;
  } else {
#pragma unroll
    for (int k = 0; k < 4; ++k) if (base + k < N) s += deg[base + k];
  }
  __shared__ int red[4];
#pragma unroll
  for (int m = 1; m < 64; m <<= 1) s += __shfl_xor(s, m);
  if ((t & 63) == 0) red[t >> 6] = s;
  __syncthreads();
  if (t == 0) bsum[blockIdx.x] = red[0] + red[1] + red[2] + red[3];
}

__global__ __launch_bounds__(256) void scan_bsum(const int* __restrict__ bsum,
                                                 int* __restrict__ boff,
                                                 int* __restrict__ off, int nb, int N) {
  __shared__ int s[256];
  __shared__ int carry_s;
  const int t = threadIdx.x;
  if (t == 0) carry_s = 0;
  __syncthreads();
  for (int base = 0; base < nb; base += 256) {
    int i = base + t;
    int v = (i < nb) ? bsum[i] : 0;
    s[t] = v;
    __syncthreads();
#pragma unroll
    for (int d = 1; d < 256; d <<= 1) {
      int u = (t >= d) ? s[t - d] : 0;
      __syncthreads();
      s[t] += u;
      __syncthreads();
    }
    int c = carry_s;
    if (i < nb) boff[i] = s[t] - v + c;
    __syncthreads();
    if (t == 0) carry_s = c + s[255];
    __syncthreads();
  }
  if (t == 0) off[N] = carry_s;
}

__global__ __launch_bounds__(256) void scan_apply(const int* __restrict__ deg,
                                                  const int* __restrict__ boff,
                                                  int* __restrict__ off,
                                                  int* __restrict__ cursor, int N) {
  const int t = threadIdx.x;
  const int base = blockIdx.x * 1024 + t * 4;
  int v0 = 0, v1 = 0, v2 = 0, v3 = 0;
  if (base + 3 < N) {
    int4 v = *(const int4*)(deg + base);
    v0 = v.x; v1 = v.y; v2 = v.z; v3 = v.w;
  } else {
    if (base + 0 < N) v0 = deg[base + 0];
    if (base + 1 < N) v1 = deg[base + 1];
    if (base + 2 < N) v2 = deg[base + 2];
  }
  const int tsum = v0 + v1 + v2 + v3;
  __shared__ int s[256];
  s[t] = tsum;
  __syncthreads();
#pragma unroll
  for (int d = 1; d < 256; d <<= 1) {
    int u = (t >= d) ? s[t - d] : 0;
    __syncthreads();
    s[t] += u;
    __syncthreads();
  }
  int exc = s[t] - tsum + boff[blockIdx.x];
  const int o1 = exc + v0, o2 = o1 + v1, o3 = o2 + v2;
  if (base + 0 < N) { off[base + 0] = exc; cursor[base + 0] = exc; }
  if (base + 1 < N) { off[base + 1] = o1;  cursor[base + 1] = o1; }
  if (base + 2 < N) { off[base + 2] = o2;  cursor[base + 2] = o2; }
  if (base + 3 < N) { off[base + 3] = o3;  cursor[base + 3] = o3; }
}

// Scatter edge payloads (single 8B int2 per edge) into dst-sorted order.
__global__ void scatter_idx2(const int* __restrict__ esrc, const int* __restrict__ edst,
                             const int* __restrict__ etype, const float* __restrict__ att,
                             int* __restrict__ cursor, int2* __restrict__ payload, int E) {
  const int e = (blockIdx.x * 256 + threadIdx.x) * 2;
  if (e + 1 < E) {
    int2 s = *(const int2*)(esrc + e);
    int2 d = *(const int2*)(edst + e);
    int2 r = *(const int2*)(etype + e);
    float2 a = *(const float2*)(att + e);
    int p0 = atomicAdd(&cursor[d.x], 1);
    int p1 = atomicAdd(&cursor[d.y], 1);
    payload[p0] = make_int2(s.x | (r.x << 24), __float_as_int(a.x));
    payload[p1] = make_int2(s.y | (r.y << 24), __float_as_int(a.y));
  } else if (e < E) {
    int pos = atomicAdd(&cursor[edst[e]], 1);
    payload[pos] = make_int2(esrc[e] | (etype[e] << 24), __float_as_int(att[e]));
  }
}

// One node per 64-lane wave: 4 edge-subgroups x 16 lanes x (4 bf16 cols).
__global__ __launch_bounds__(256, 8) void node_gather(const int* __restrict__ off,
                                                      const int2* __restrict__ payload,
                                                      const ushort_t* __restrict__ proj,
                                                      const float* __restrict__ hbias,
                                                      float* __restrict__ out, int N) {
  const int n = (blockIdx.x * 256 + threadIdx.x) >> 6;
  if (n >= N) return;
  const int lane = threadIdx.x & 63;
  const int sub = lane >> 4;
  const int q = lane & 15;

  const int s0 = off[n], s1 = off[n + 1];
  float4 acc = make_float4(0.f, 0.f, 0.f, 0.f);
  float sa = 0.f;
  for (int e = s0 + sub; e < s1; e += 4) {
    const int2 pe = payload[e];
    const float a = __int_as_float(pe.y);
    const int src = pe.x & 0x00FFFFFF;
    const int r = ((unsigned)pe.x) >> 24;
    const ushort4 p = *(const ushort4*)(proj + ((size_t)r * N + src) * D + q * 4);
    acc.x = fmaf(a, bf2f(p.x), acc.x);
    acc.y = fmaf(a, bf2f(p.y), acc.y);
    acc.z = fmaf(a, bf2f(p.z), acc.z);
    acc.w = fmaf(a, bf2f(p.w), acc.w);
    sa += a;
  }
#pragma unroll
  for (int m = 16; m < 64; m <<= 1) {
    acc.x += __shfl_xor(acc.x, m);
    acc.y += __shfl_xor(acc.y, m);
    acc.z += __shfl_xor(acc.z, m);
    acc.w += __shfl_xor(acc.w, m);
    sa += __shfl_xor(sa, m);
  }
  if (sub == 0) {
    const float4 hb = ((const float4*)hbias)[q];
    float* op = out + (size_t)n * D + q * 4;
    float4 cur = *(float4*)op;      // self-loop already there
    cur.x += acc.x + sa * hb.x;
    cur.y += acc.y + sa * hb.y;
    cur.z += acc.z + sa * hb.z;
    cur.w += acc.w + sa * hb.w;
    *(float4*)op = cur;
  }
}

// ---------------- fallback: atomic scatter (float proj) ----------------
__global__ __launch_bounds__(256, 8) void edge_scatter(const int* __restrict__ esrc,
                                                       const int* __restrict__ edst,
                                                       const int* __restrict__ etype,
                                                       const float* __restrict__ att,
                                                       const float* __restrict__ proj,
                                                       const float* __restrict__ hbias,
                                                       float* __restrict__ out,
                                                       int E, int N, int relFilter) {
  const int t = blockIdx.x * 256 + threadIdx.x;
  const int wave = t >> 6;
  const int lane = threadIdx.x & 63;
  const int sub = lane >> 4;
  const int q = lane & 15;
  const long e = (long)wave * 4 + sub;
  if (e >= E) return;
  const int r = etype[e];
  if (relFilter >= 0 && r != relFilter) return;
  const int s = esrc[e];
  const int dn = edst[e];
  const float a = att[e];
  const size_t base = (relFilter >= 0) ? (size_t)s * D : ((size_t)r * N + s) * D;
  const float4 hb = ((const float4*)hbias)[q];
  const float4 p = *(const float4*)(proj + base + q * 4);
  float* op = out + (size_t)dn * D + q * 4;
  unsafeAtomicAdd(op + 0, (p.x + hb.x) * a);
  unsafeAtomicAdd(op + 1, (p.y + hb.y) * a);
  unsafeAtomicAdd(op + 2, (p.z + hb.z) * a);
  unsafeAtomicAdd(op + 3, (p.w + hb.w) * a);
}

extern "C" void kernel_launch(void* const* d_in, const int* in_sizes, int n_in,
                              void* d_out, int out_size, void* d_ws, size_t ws_size,
                              hipStream_t stream) {
  const float* feat   = (const float*)d_in[0];
  const int* esrc     = (const int*)d_in[1];
  const int* edst     = (const int*)d_in[2];
  const int* etype    = (const int*)d_in[3];
  const float* att    = (const float*)d_in[4];
  const float* weight = (const float*)d_in[5];
  const float* hbias  = (const float*)d_in[6];
  const float* loopw  = (const float*)d_in[7];
  float* out = (float*)d_out;

  const int N = in_sizes[0] / D;          // 50000
  const int E = in_sizes[1];              // 800000
  const int R = in_sizes[5] / (D * D);    // 8

  const int Npad = (N + 3) & ~3;
  const int nb = (N + 1023) / 1024;

  // Sorted-CSR fast path layout (bf16 proj):
  const size_t projBytes = (size_t)R * N * D * 2;
  const size_t intCount  = (size_t)Npad + (size_t)(N + 1) + (size_t)N + (size_t)nb;
  const size_t payOff    = (projBytes + intCount * 4 + 7) & ~(size_t)7;
  const size_t needSorted = payOff + (size_t)E * 8;

  const int tilesN = (N + 127) / 128;
  const int mGroups = (R + 1 + 2) / 3;    // 3 matrices per block
  const int epairBlocks = ((E + 1) / 2 + 255) / 256;

  if (ws_size >= needSorted) {
    ushort_t* proj = (ushort_t*)d_ws;
    int* deg    = (int*)((char*)d_ws + projBytes);  // Npad ints, 16B-aligned
    int* off    = deg + Npad;                       // N+1
    int* cursor = off + (N + 1);                    // N
    int* bsum   = cursor + N;                       // nb (doubles as boff)
    int2* payload = (int2*)((char*)d_ws + payOff);  // E

    proj_fused<<<dim3(tilesN, mGroups), 256, 0, stream>>>(feat, weight, loopw, proj, out, N, R);
    zero_ints<<<(N + 255) / 256, 256, 0, stream>>>(deg, N);
    hist_dst2<<<epairBlocks, 256, 0, stream>>>(edst, deg, E);
    scan_partial<<<nb, 256, 0, stream>>>(deg, bsum, N);
    scan_bsum<<<1, 256, 0, stream>>>(bsum, bsum, off, nb, N);
    scan_apply<<<nb, 256, 0, stream>>>(deg, bsum, off, cursor, N);
    scatter_idx2<<<epairBlocks, 256, 0, stream>>>(esrc, edst, etype, att, cursor, payload, E);
    node_gather<<<(N + 3) / 4, 256, 0, stream>>>(off, payload, proj, hbias, out, N);
  } else {
    // Minimal-scratch fallback: needs N*D floats.
    const int eblocks16 = (E + 15) / 16;
    proj_single<<<tilesN, 256, 0, stream>>>(feat, loopw, out, N);
    for (int r = 0; r < R; ++r) {
      proj_single<<<tilesN, 256, 0, stream>>>(feat, weight + (size_t)r * D * D,
                                              (float*)d_ws, N);
      edge_scatter<<<eblocks16, 256, 0, stream>>>(esrc, edst, etype, att, (float*)d_ws,
                                                  hbias, out, E, N, r);
    }
  }
}

// Round 7
// 140.656 us; speedup vs baseline: 1.5804x; 1.3595x over previous
//
#include <hip/hip_runtime.h>

#define D 64  // D_IN == D_OUT == 64

typedef unsigned short ushort_t;
typedef __attribute__((ext_vector_type(8))) short bf16x8;
typedef __attribute__((ext_vector_type(4))) float f32x4;

__device__ __forceinline__ void fma4(float4& c, float a, const float4& b) {
  c.x = fmaf(a, b.x, c.x);
  c.y = fmaf(a, b.y, c.y);
  c.z = fmaf(a, b.z, c.z);
  c.w = fmaf(a, b.w, c.w);
}

__device__ __forceinline__ unsigned short f2bf(float f) {  // RNE pack
  unsigned u = __float_as_uint(f);
  return (unsigned short)((u + 0x7FFFu + ((u >> 16) & 1u)) >> 16);
}
__device__ __forceinline__ float bf2f(unsigned short h) {
  return __uint_as_float((unsigned)h << 16);
}

__device__ __forceinline__ bf16x8 pack_bf8(float4 v0, float4 v1) {
  bf16x8 r;
  r[0] = (short)f2bf(v0.x); r[1] = (short)f2bf(v0.y);
  r[2] = (short)f2bf(v0.z); r[3] = (short)f2bf(v0.w);
  r[4] = (short)f2bf(v1.x); r[5] = (short)f2bf(v1.y);
  r[6] = (short)f2bf(v1.z); r[7] = (short)f2bf(v1.w);
  return r;
}

// ---------------- MFMA projection ----------------
// Block = 128 threads (2 waves); each wave owns 16 nodes -> 32 nodes/block.
// A-frags (feat rows, bf16) loaded ONCE, reused across all R+1 matrices.
// Per matrix: stage W^T bf16 in LDS (9.2 KB), 8 ds_read_b128 + 8 MFMA per wave.
// m<R -> bf16 proj[m]; m==R -> fp32 self-loop into out.
__global__ __launch_bounds__(128) void proj_mfma(const float* __restrict__ feat,
                                                 const float* __restrict__ weight,
                                                 const float* __restrict__ loopw,
                                                 ushort_t* __restrict__ proj,
                                                 float* __restrict__ out, int N, int R) {
  __shared__ ushort_t Wt[64][72];   // Wt[col][k], row stride 144B (16B-mult)
  const int t = threadIdx.x;
  const int lane = t & 63;
  const int wid = t >> 6;
  const int rowBase = blockIdx.x * 32 + wid * 16;

  // A-fragments: lane holds feat[row = rowBase + (lane&15)][k = kh*32 + 8*(lane>>4) + j]
  const int arow = rowBase + (lane & 15);
  const int kb = (lane >> 4) * 8;
  bf16x8 a[2];
#pragma unroll
  for (int kh = 0; kh < 2; ++kh) {
    float4 v0 = make_float4(0.f, 0.f, 0.f, 0.f);
    float4 v1 = v0;
    if (arow < N) {
      const float* p = feat + (size_t)arow * D + kh * 32 + kb;
      v0 = *(const float4*)p;
      v1 = *(const float4*)(p + 4);
    }
    a[kh] = pack_bf8(v0, v1);
  }

  const int ccol = lane & 15;
  const int crow0 = rowBase + (lane >> 4) * 4;

  for (int m = 0; m <= R; ++m) {
    const float* W = (m < R) ? weight + (size_t)m * D * D : loopw;
    __syncthreads();
    // Stage W transposed as bf16: Wt[c][k] = bf16(W[k*64+c]).
    for (int i = t; i < 1024; i += 128) {
      float4 w = ((const float4*)W)[i];
      int flat = 4 * i;
      int k = flat >> 6, c = flat & 63;
      Wt[c + 0][k] = f2bf(w.x);
      Wt[c + 1][k] = f2bf(w.y);
      Wt[c + 2][k] = f2bf(w.z);
      Wt[c + 3][k] = f2bf(w.w);
    }
    __syncthreads();

    f32x4 acc[4];
#pragma unroll
    for (int ct = 0; ct < 4; ++ct) {
      acc[ct] = (f32x4){0.f, 0.f, 0.f, 0.f};
      bf16x8 b0 = *(const bf16x8*)&Wt[ccol + 16 * ct][kb];        // k in [0,32)
      bf16x8 b1 = *(const bf16x8*)&Wt[ccol + 16 * ct][kb + 32];   // k in [32,64)
      acc[ct] = __builtin_amdgcn_mfma_f32_16x16x32_bf16(a[0], b0, acc[ct], 0, 0, 0);
      acc[ct] = __builtin_amdgcn_mfma_f32_16x16x32_bf16(a[1], b1, acc[ct], 0, 0, 0);
    }

    if (m < R) {
      ushort_t* op = proj + (size_t)m * N * D;
#pragma unroll
      for (int r = 0; r < 4; ++r) {
        const int gr = crow0 + r;
        if (gr < N) {
#pragma unroll
          for (int ct = 0; ct < 4; ++ct)
            op[(size_t)gr * D + ct * 16 + ccol] = f2bf(acc[ct][r]);
        }
      }
    } else {
#pragma unroll
      for (int r = 0; r < 4; ++r) {
        const int gr = crow0 + r;
        if (gr < N) {
#pragma unroll
          for (int ct = 0; ct < 4; ++ct)
            out[(size_t)gr * D + ct * 16 + ccol] = acc[ct][r];
        }
      }
    }
  }
}

// ---------------- float-only tile (fallback path) ----------------
__global__ __launch_bounds__(256, 3) void proj_single(const float* __restrict__ feat,
                                                      const float* __restrict__ W,
                                                      float* __restrict__ outp, int N) {
  __shared__ float sW[64 * 64];
  __shared__ float sF[64 * 132];
  const int t = threadIdx.x;
  const int tileBase = blockIdx.x * 128;

  {
    const float4* Wv = (const float4*)W;
    float4* sWv = (float4*)sW;
    for (int k = t; k < 1024; k += 256) sWv[k] = Wv[k];
  }
  {
    const int row = t >> 1, half = t & 1;
    const int gr = tileBase + row;
    if (gr < N) {
      const float4* src = (const float4*)(feat + (size_t)gr * D + half * 32);
#pragma unroll
      for (int k = 0; k < 8; ++k) {
        float4 v = src[k];
        int i0 = half * 32 + k * 4;
        sF[(i0 + 0) * 132 + row] = v.x;
        sF[(i0 + 1) * 132 + row] = v.y;
        sF[(i0 + 2) * 132 + row] = v.z;
        sF[(i0 + 3) * 132 + row] = v.w;
      }
    } else {
#pragma unroll
      for (int k = 0; k < 8; ++k) {
        int i0 = half * 32 + k * 4;
        sF[(i0 + 0) * 132 + row] = 0.f;
        sF[(i0 + 1) * 132 + row] = 0.f;
        sF[(i0 + 2) * 132 + row] = 0.f;
        sF[(i0 + 3) * 132 + row] = 0.f;
      }
    }
  }
  __syncthreads();

  const int c0 = (t & 15) * 4;
  const int r0 = (t >> 4) * 8;
  float4 acc[8];
#pragma unroll
  for (int rr = 0; rr < 8; ++rr) acc[rr] = make_float4(0.f, 0.f, 0.f, 0.f);

#pragma unroll 8
  for (int i = 0; i < 64; ++i) {
    float4 w  = *(const float4*)&sW[i * 64 + c0];
    float4 a0 = *(const float4*)&sF[i * 132 + r0];
    float4 a1 = *(const float4*)&sF[i * 132 + r0 + 4];
    fma4(acc[0], a0.x, w); fma4(acc[1], a0.y, w);
    fma4(acc[2], a0.z, w); fma4(acc[3], a0.w, w);
    fma4(acc[4], a1.x, w); fma4(acc[5], a1.y, w);
    fma4(acc[6], a1.z, w); fma4(acc[7], a1.w, w);
  }

#pragma unroll
  for (int rr = 0; rr < 8; ++rr) {
    int gn = tileBase + r0 + rr;
    if (gn < N) *(float4*)(outp + (size_t)gn * D + c0) = acc[rr];
  }
}

// ---------------- CSR build ----------------
__global__ void zero_ints(int* __restrict__ p, int n) {
  int i = blockIdx.x * 256 + threadIdx.x;
  if (i < n) p[i] = 0;
}

// Histogram + per-edge rank in one pass (rank write is coalesced).
__global__ void hist_rank(const int* __restrict__ edst, int* __restrict__ deg,
                          int* __restrict__ rank, int E) {
  const int e = (blockIdx.x * 256 + threadIdx.x) * 2;
  if (e + 1 < E) {
    int2 d = *(const int2*)(edst + e);
    int r0 = atomicAdd(&deg[d.x], 1);
    int r1 = atomicAdd(&deg[d.y], 1);
    *(int2*)(rank + e) = make_int2(r0, r1);
  } else if (e < E) {
    rank[e] = atomicAdd(&deg[edst[e]], 1);
  }
}

__global__ __launch_bounds__(256) void scan_partial(const int* __restrict__ deg,
                                                    int* __restrict__ bsum, int N) {
  const int t = threadIdx.x;
  const int base = blockIdx.x * 1024 + t * 4;
  int s = 0;
  if (base + 3 < N) {
    int4 v = *(const int4*)(deg + base);
    s = v.x + v.y + v.z + v.w;
  } else {
#pragma unroll
    for (int k = 0; k < 4; ++k) if (base + k < N) s += deg[base + k];
  }
  __shared__ int red[4];
#pragma unroll
  for (int m = 1; m < 64; m <<= 1) s += __shfl_xor(s, m);
  if ((t & 63) == 0) red[t >> 6] = s;
  __syncthreads();
  if (t == 0) bsum[blockIdx.x] = red[0] + red[1] + red[2] + red[3];
}

__global__ __launch_bounds__(256) void scan_bsum(const int* __restrict__ bsum,
                                                 int* __restrict__ boff,
                                                 int* __restrict__ off, int nb, int N) {
  __shared__ int s[256];
  __shared__ int carry_s;
  const int t = threadIdx.x;
  if (t == 0) carry_s = 0;
  __syncthreads();
  for (int base = 0; base < nb; base += 256) {
    int i = base + t;
    int v = (i < nb) ? bsum[i] : 0;
    s[t] = v;
    __syncthreads();
#pragma unroll
    for (int d = 1; d < 256; d <<= 1) {
      int u = (t >= d) ? s[t - d] : 0;
      __syncthreads();
      s[t] += u;
      __syncthreads();
    }
    int c = carry_s;
    if (i < nb) boff[i] = s[t] - v + c;
    __syncthreads();
    if (t == 0) carry_s = c + s[255];
    __syncthreads();
  }
  if (t == 0) off[N] = carry_s;
}

__global__ __launch_bounds__(256) void scan_apply(const int* __restrict__ deg,
                                                  const int* __restrict__ boff,
                                                  int* __restrict__ off, int N) {
  const int t = threadIdx.x;
  const int base = blockIdx.x * 1024 + t * 4;
  int v0 = 0, v1 = 0, v2 = 0, v3 = 0;
  if (base + 3 < N) {
    int4 v = *(const int4*)(deg + base);
    v0 = v.x; v1 = v.y; v2 = v.z; v3 = v.w;
  } else {
    if (base + 0 < N) v0 = deg[base + 0];
    if (base + 1 < N) v1 = deg[base + 1];
    if (base + 2 < N) v2 = deg[base + 2];
  }
  const int tsum = v0 + v1 + v2 + v3;
  __shared__ int s[256];
  s[t] = tsum;
  __syncthreads();
#pragma unroll
  for (int d = 1; d < 256; d <<= 1) {
    int u = (t >= d) ? s[t - d] : 0;
    __syncthreads();
    s[t] += u;
    __syncthreads();
  }
  int exc = s[t] - tsum + boff[blockIdx.x];
  const int o1 = exc + v0, o2 = o1 + v1, o3 = o2 + v2;
  if (base + 0 < N) off[base + 0] = exc;
  if (base + 1 < N) off[base + 1] = o1;
  if (base + 2 < N) off[base + 2] = o2;
  if (base + 3 < N) off[base + 3] = o3;
}

// Scatter payloads using precomputed rank: pos = off[dst] + rank. No atomics.
__global__ void scatter_pos(const int* __restrict__ esrc, const int* __restrict__ edst,
                            const int* __restrict__ etype, const float* __restrict__ att,
                            const int* __restrict__ off, const int* __restrict__ rank,
                            int2* __restrict__ payload, int E) {
  const int e = (blockIdx.x * 256 + threadIdx.x) * 4;
  if (e + 3 < E) {
    int4 s  = *(const int4*)(esrc + e);
    int4 d  = *(const int4*)(edst + e);
    int4 ty = *(const int4*)(etype + e);
    float4 a = *(const float4*)(att + e);
    int4 rk = *(const int4*)(rank + e);
    payload[off[d.x] + rk.x] = make_int2(s.x | (ty.x << 24), __float_as_int(a.x));
    payload[off[d.y] + rk.y] = make_int2(s.y | (ty.y << 24), __float_as_int(a.y));
    payload[off[d.z] + rk.z] = make_int2(s.z | (ty.z << 24), __float_as_int(a.z));
    payload[off[d.w] + rk.w] = make_int2(s.w | (ty.w << 24), __float_as_int(a.w));
  } else {
    for (int i = e; i < E; ++i)
      payload[off[edst[i]] + rank[i]] =
          make_int2(esrc[i] | (etype[i] << 24), __float_as_int(att[i]));
  }
}

// One node per 64-lane wave: 4 edge-subgroups x 16 lanes x (4 bf16 cols).
__global__ __launch_bounds__(256, 8) void node_gather(const int* __restrict__ off,
                                                      const int2* __restrict__ payload,
                                                      const ushort_t* __restrict__ proj,
                                                      const float* __restrict__ hbias,
                                                      float* __restrict__ out, int N) {
  const int n = (blockIdx.x * 256 + threadIdx.x) >> 6;
  if (n >= N) return;
  const int lane = threadIdx.x & 63;
  const int sub = lane >> 4;
  const int q = lane & 15;

  const int s0 = off[n], s1 = off[n + 1];
  float4 acc = make_float4(0.f, 0.f, 0.f, 0.f);
  float sa = 0.f;
  for (int e = s0 + sub; e < s1; e += 4) {
    const int2 pe = payload[e];
    const float a = __int_as_float(pe.y);
    const int src = pe.x & 0x00FFFFFF;
    const int r = ((unsigned)pe.x) >> 24;
    const ushort4 p = *(const ushort4*)(proj + ((size_t)r * N + src) * D + q * 4);
    acc.x = fmaf(a, bf2f(p.x), acc.x);
    acc.y = fmaf(a, bf2f(p.y), acc.y);
    acc.z = fmaf(a, bf2f(p.z), acc.z);
    acc.w = fmaf(a, bf2f(p.w), acc.w);
    sa += a;
  }
#pragma unroll
  for (int m = 16; m < 64; m <<= 1) {
    acc.x += __shfl_xor(acc.x, m);
    acc.y += __shfl_xor(acc.y, m);
    acc.z += __shfl_xor(acc.z, m);
    acc.w += __shfl_xor(acc.w, m);
    sa += __shfl_xor(sa, m);
  }
  if (sub == 0) {
    const float4 hb = ((const float4*)hbias)[q];
    float* op = out + (size_t)n * D + q * 4;
    float4 cur = *(float4*)op;      // self-loop already there
    cur.x += acc.x + sa * hb.x;
    cur.y += acc.y + sa * hb.y;
    cur.z += acc.z + sa * hb.z;
    cur.w += acc.w + sa * hb.w;
    *(float4*)op = cur;
  }
}

// ---------------- fallback: atomic scatter (float proj) ----------------
__global__ __launch_bounds__(256, 8) void edge_scatter(const int* __restrict__ esrc,
                                                       const int* __restrict__ edst,
                                                       const int* __restrict__ etype,
                                                       const float* __restrict__ att,
                                                       const float* __restrict__ proj,
                                                       const float* __restrict__ hbias,
                                                       float* __restrict__ out,
                                                       int E, int N, int relFilter) {
  const int t = blockIdx.x * 256 + threadIdx.x;
  const int wave = t >> 6;
  const int lane = threadIdx.x & 63;
  const int sub = lane >> 4;
  const int q = lane & 15;
  const long e = (long)wave * 4 + sub;
  if (e >= E) return;
  const int r = etype[e];
  if (relFilter >= 0 && r != relFilter) return;
  const int s = esrc[e];
  const int dn = edst[e];
  const float a = att[e];
  const size_t base = (relFilter >= 0) ? (size_t)s * D : ((size_t)r * N + s) * D;
  const float4 hb = ((const float4*)hbias)[q];
  const float4 p = *(const float4*)(proj + base + q * 4);
  float* op = out + (size_t)dn * D + q * 4;
  unsafeAtomicAdd(op + 0, (p.x + hb.x) * a);
  unsafeAtomicAdd(op + 1, (p.y + hb.y) * a);
  unsafeAtomicAdd(op + 2, (p.z + hb.z) * a);
  unsafeAtomicAdd(op + 3, (p.w + hb.w) * a);
}

extern "C" void kernel_launch(void* const* d_in, const int* in_sizes, int n_in,
                              void* d_out, int out_size, void* d_ws, size_t ws_size,
                              hipStream_t stream) {
  const float* feat   = (const float*)d_in[0];
  const int* esrc     = (const int*)d_in[1];
  const int* edst     = (const int*)d_in[2];
  const int* etype    = (const int*)d_in[3];
  const float* att    = (const float*)d_in[4];
  const float* weight = (const float*)d_in[5];
  const float* hbias  = (const float*)d_in[6];
  const float* loopw  = (const float*)d_in[7];
  float* out = (float*)d_out;

  const int N = in_sizes[0] / D;          // 50000
  const int E = in_sizes[1];              // 800000
  const int R = in_sizes[5] / (D * D);    // 8

  const int Npad = (N + 3) & ~3;
  const int nb = (N + 1023) / 1024;

  // Fast-path workspace layout (bf16 proj):
  const size_t projBytes = (size_t)R * N * D * 2;
  const size_t intCount  = (size_t)Npad + (size_t)(N + 1) + (size_t)nb + (size_t)E;
  const size_t payOff    = (projBytes + intCount * 4 + 7) & ~(size_t)7;
  const size_t needSorted = payOff + (size_t)E * 8;

  const int projBlocks = (N + 31) / 32;
  const int epairBlocks = ((E + 1) / 2 + 255) / 256;
  const int equadBlocks = ((E + 3) / 4 + 255) / 256;

  if (ws_size >= needSorted) {
    ushort_t* proj = (ushort_t*)d_ws;
    int* deg    = (int*)((char*)d_ws + projBytes);  // Npad ints, 16B-aligned
    int* off    = deg + Npad;                       // N+1
    int* bsum   = off + (N + 1);                    // nb (doubles as boff)
    int* rank   = bsum + nb;                        // E
    int2* payload = (int2*)((char*)d_ws + payOff);  // E

    proj_mfma<<<projBlocks, 128, 0, stream>>>(feat, weight, loopw, proj, out, N, R);
    zero_ints<<<(N + 255) / 256, 256, 0, stream>>>(deg, N);
    hist_rank<<<epairBlocks, 256, 0, stream>>>(edst, deg, rank, E);
    scan_partial<<<nb, 256, 0, stream>>>(deg, bsum, N);
    scan_bsum<<<1, 256, 0, stream>>>(bsum, bsum, off, nb, N);
    scan_apply<<<nb, 256, 0, stream>>>(deg, bsum, off, N);
    scatter_pos<<<equadBlocks, 256, 0, stream>>>(esrc, edst, etype, att, off, rank,
                                                 payload, E);
    node_gather<<<(N + 3) / 4, 256, 0, stream>>>(off, payload, proj, hbias, out, N);
  } else {
    // Minimal-scratch fallback: needs N*D floats.
    const int tilesN = (N + 127) / 128;
    const int eblocks16 = (E + 15) / 16;
    proj_single<<<tilesN, 256, 0, stream>>>(feat, loopw, out, N);
    for (int r = 0; r < R; ++r) {
      proj_single<<<tilesN, 256, 0, stream>>>(feat, weight + (size_t)r * D * D,
                                              (float*)d_ws, N);
      edge_scatter<<<eblocks16, 256, 0, stream>>>(esrc, edst, etype, att, (float*)d_ws,
                                                  hbias, out, E, N, r);
    }
  }
}